// Round 1
// baseline (495.115 us; speedup 1.0000x reference)
//
#include <hip/hip_runtime.h>
#include <math.h>

#define BATCH   131072
#define OUTD    700
#define H1D     25
#define H2D     20
#define SPI     8                          // samples per iteration
#define NITER   8                          // iterations per block
#define NBLK    (BATCH / (SPI * NITER))    // 2048 blocks
#define BLK     256

__global__ __launch_bounds__(BLK) void nndpf_kernel(
    const float* __restrict__ x,
    const float* __restrict__ W1, const float* __restrict__ b1,
    const float* __restrict__ W2, const float* __restrict__ b2,
    const float* __restrict__ W3, const float* __restrict__ b3,
    float* __restrict__ out)
{
    __shared__ double w1d[2 * H1D];
    __shared__ double b1d[H1D];
    __shared__ double w2d[H1D * H2D];
    __shared__ double b2d[H2D];
    __shared__ float  xgs[50];
    __shared__ double cwd[50];             // trapz weights c_i (f64)
    __shared__ double cgd[4][H2D];         // reduced weights: denom_q = cbd[q] + sum_k h2[k]*cgd[q][k]
    __shared__ double cbd[4];
    __shared__ double h1d[SPI][H1D];
    __shared__ double h2d[SPI][H2D];
    __shared__ __align__(16) float h2f[SPI][H2D];
    __shared__ float4 sclv[SPI];           // per-sample scales {1/g, 3/v, 1/v3, 3/v8}

    const int t = threadIdx.x;

    // ---------------- setup (once per block) ----------------
    if (t < 2 * H1D) w1d[t] = (double)W1[t];
    if (t < H1D)     b1d[t] = (double)b1[t];
    for (int i = t; i < H1D * H2D; i += BLK) w2d[i] = (double)W2[i];
    if (t < H2D)     b2d[t] = (double)b2[t];
    if (t < 50) {
        // match np.logspace(-7,0,50).astype(float32): y = i*delta + start in f64
        // (separate mul/add like np.linspace; volatile blocks fma contraction),
        // endpoint set exactly -> 10^0 = 1.0
        volatile double m = (double)t * (7.0 / 49.0);
        double e = m + (-7.0);
        xgs[t] = (t == 49) ? 1.0f : (float)pow(10.0, e);
    }

    // W3 columns into registers (f32): thread t owns columns t, t+256, t+512
    float w3r[3][H2D];
    float b3r[3];
    #pragma unroll
    for (int c = 0; c < 3; ++c) {
        const int j = t + BLK * c;
        if (j < OUTD) {
            b3r[c] = b3[j];
            #pragma unroll
            for (int k = 0; k < H2D; ++k) w3r[c][k] = W3[k * OUTD + j];
        } else {
            b3r[c] = 0.0f;
            #pragma unroll
            for (int k = 0; k < H2D; ++k) w3r[c][k] = 0.0f;
        }
    }
    __syncthreads();

    // trapz weights: c_0=0.5(x1-x0), c_49=0.5(x49-x48), else 0.5(x_{i+1}-x_{i-1})
    if (t < 50) {
        float xp = (t < 49) ? xgs[t + 1] : xgs[t];
        float xm = (t > 0)  ? xgs[t - 1] : xgs[t];
        cwd[t] = 0.5 * ((double)xp - (double)xm);
    }
    __syncthreads();

    // reduced weights: the trapz denominators are affine in h2 (o = h2@W3 + b3)
    if (t < 4 * H2D) {
        const int q = t / H2D, k = t % H2D;
        const float* col = W3 + k * OUTD;
        double acc = 0.0;
        if (q == 0) {            // g_sigma: slices [50,100)+[100,150)
            for (int i = 0; i < 50; ++i)
                acc = fma(cwd[i], (double)col[50 + i] + (double)col[100 + i], acc);
        } else {                 // v:[150,200) v3:[200,250) v8:[250,300)
            const int off = 100 + 50 * q;
            for (int i = 0; i < 50; ++i)
                acc = fma(cwd[i], (double)col[off + i], acc);
        }
        cgd[q][k] = acc;
    }
    if (t < 4) {
        const int q = t;
        double acc = 0.0;
        if (q == 0) {
            for (int i = 0; i < 50; ++i)
                acc = fma(cwd[i], (double)b3[50 + i] + (double)b3[100 + i], acc);
        } else {
            const int off = 100 + 50 * q;
            for (int i = 0; i < 50; ++i)
                acc = fma(cwd[i], (double)b3[off + i], acc);
        }
        cbd[q] = acc;
    }
    __syncthreads();

    // scale bucket per owned column (0 = unscaled, 1..4 = component of sclv)
    int bkt[3];
    #pragma unroll
    for (int c = 0; c < 3; ++c) {
        const int j = t + BLK * c;
        int b = 0;
        if      (j >= 50  && j < 150) b = 1;
        else if (j >= 150 && j < 200) b = 2;
        else if (j >= 200 && j < 250) b = 3;
        else if (j >= 250 && j < 300) b = 4;
        bkt[c] = b;
    }

    // ---------------- main loop: 8 samples per iteration ----------------
    for (int it = 0; it < NITER; ++it) {
        const int base = (blockIdx.x * NITER + it) * SPI;

        // h1 = tanh(x@W1 + b1)   (f64, 200 threads)
        if (t < SPI * H1D) {
            const int s = t / H1D, k = t % H1D;
            const double x0 = (double)x[(base + s) * 2 + 0];
            const double x1 = (double)x[(base + s) * 2 + 1];
            h1d[s][k] = tanh(fma(x0, w1d[k], fma(x1, w1d[H1D + k], b1d[k])));
        }
        __syncthreads();

        // h2 = tanh(h1@W2 + b2)  (f64, 160 threads)
        if (t < SPI * H2D) {
            const int s = t / H2D, m = t % H2D;
            double acc = b2d[m];
            #pragma unroll
            for (int k = 0; k < H1D; ++k) acc = fma(h1d[s][k], w2d[k * H2D + m], acc);
            const double h = tanh(acc);
            h2d[s][m] = h;
            h2f[s][m] = (float)h;
        }
        __syncthreads();

        // scales: f64 20-term dots (32 threads; the ill-conditioned part)
        if (t < SPI * 4) {
            const int s = t >> 2, q = t & 3;
            double acc = cbd[q];
            #pragma unroll
            for (int k = 0; k < H2D; ++k) acc = fma(h2d[s][k], cgd[q][k], acc);
            const double num = (q & 1) ? 3.0 : 1.0;   // 1/g, 3/v, 1/v3, 3/v8
            ((float*)&sclv[s])[q] = (float)(num / acc);
        }
        __syncthreads();

        // o = h2@W3 + b3 (f32), apply scale, coalesced store
        #pragma unroll
        for (int s = 0; s < SPI; ++s) {
            float h[H2D];
            #pragma unroll
            for (int q5 = 0; q5 < 5; ++q5) {
                const float4 hv = *reinterpret_cast<const float4*>(&h2f[s][4 * q5]);
                h[4 * q5 + 0] = hv.x; h[4 * q5 + 1] = hv.y;
                h[4 * q5 + 2] = hv.z; h[4 * q5 + 3] = hv.w;
            }
            const float4 sv = sclv[s];
            const size_t row = (size_t)(base + s) * OUTD;
            #pragma unroll
            for (int c = 0; c < 3; ++c) {
                const int j = t + BLK * c;
                if (j < OUTD) {
                    float acc = b3r[c];
                    #pragma unroll
                    for (int k = 0; k < H2D; ++k) acc = fmaf(h[k], w3r[c][k], acc);
                    float sc = 1.0f;
                    if      (bkt[c] == 1) sc = sv.x;
                    else if (bkt[c] == 2) sc = sv.y;
                    else if (bkt[c] == 3) sc = sv.z;
                    else if (bkt[c] == 4) sc = sv.w;
                    out[row + j] = acc * sc;
                }
            }
        }
        // no trailing barrier needed: next iter's LDS writes are fenced by the
        // barriers above before any array read in this iter can be overwritten
    }
}

extern "C" void kernel_launch(void* const* d_in, const int* in_sizes, int n_in,
                              void* d_out, int out_size, void* d_ws, size_t ws_size,
                              hipStream_t stream) {
    const float* x  = (const float*)d_in[0];
    const float* W1 = (const float*)d_in[1];
    const float* b1 = (const float*)d_in[2];
    const float* W2 = (const float*)d_in[3];
    const float* b2 = (const float*)d_in[4];
    const float* W3 = (const float*)d_in[5];
    const float* b3 = (const float*)d_in[6];
    float* out = (float*)d_out;

    hipLaunchKernelGGL(nndpf_kernel, dim3(NBLK), dim3(BLK), 0, stream,
                       x, W1, b1, W2, b2, W3, b3, out);
}

// Round 2
// 458.560 us; speedup vs baseline: 1.0797x; 1.0797x over previous
//
#include <hip/hip_runtime.h>
#include <math.h>

#define BATCH   131072
#define OUTD    700
#define H1D     25
#define H2D     20

// ---------------- K1: per-sample f64 front-end ----------------
// One thread = one sample. Arithmetic is bit-identical to the R0 kernel:
// same fma chains, same OCML tanh/pow, same op order. Writes h2 (f32) and
// the 4 scales per sample to workspace.
#define K1_BLK  256
#define K1_NBLK (BATCH / K1_BLK)   // 512

__global__ __launch_bounds__(K1_BLK) void frontend_kernel(
    const float* __restrict__ x,
    const float* __restrict__ W1, const float* __restrict__ b1,
    const float* __restrict__ W2, const float* __restrict__ b2,
    const float* __restrict__ W3, const float* __restrict__ b3,
    float* __restrict__ h2f_out, float4* __restrict__ scl_out)
{
    __shared__ double w1d[2 * H1D];
    __shared__ double b1d[H1D];
    __shared__ double w2d[H1D * H2D];
    __shared__ double b2d[H2D];
    __shared__ float  xgs[50];
    __shared__ double cwd[50];
    __shared__ double cgd[4][H2D];
    __shared__ double cbd[4];

    const int t = threadIdx.x;

    if (t < 2 * H1D) w1d[t] = (double)W1[t];
    if (t < H1D)     b1d[t] = (double)b1[t];
    for (int i = t; i < H1D * H2D; i += K1_BLK) w2d[i] = (double)W2[i];
    if (t < H2D)     b2d[t] = (double)b2[t];
    if (t < 50) {
        // match np.logspace(-7,0,50).astype(float32); volatile blocks fma
        volatile double m = (double)t * (7.0 / 49.0);
        double e = m + (-7.0);
        xgs[t] = (t == 49) ? 1.0f : (float)pow(10.0, e);
    }
    __syncthreads();

    if (t < 50) {
        float xp = (t < 49) ? xgs[t + 1] : xgs[t];
        float xm = (t > 0)  ? xgs[t - 1] : xgs[t];
        cwd[t] = 0.5 * ((double)xp - (double)xm);
    }
    __syncthreads();

    if (t < 4 * H2D) {
        const int q = t / H2D, k = t % H2D;
        const float* col = W3 + k * OUTD;
        double acc = 0.0;
        if (q == 0) {
            for (int i = 0; i < 50; ++i)
                acc = fma(cwd[i], (double)col[50 + i] + (double)col[100 + i], acc);
        } else {
            const int off = 100 + 50 * q;
            for (int i = 0; i < 50; ++i)
                acc = fma(cwd[i], (double)col[off + i], acc);
        }
        cgd[q][k] = acc;
    }
    if (t < 4) {
        const int q = t;
        double acc = 0.0;
        if (q == 0) {
            for (int i = 0; i < 50; ++i)
                acc = fma(cwd[i], (double)b3[50 + i] + (double)b3[100 + i], acc);
        } else {
            const int off = 100 + 50 * q;
            for (int i = 0; i < 50; ++i)
                acc = fma(cwd[i], (double)b3[off + i], acc);
        }
        cbd[q] = acc;
    }
    __syncthreads();

    // ---- per-sample pipeline, no barriers, registers only ----
    const int sid = blockIdx.x * K1_BLK + t;
    const double x0 = (double)x[sid * 2 + 0];
    const double x1 = (double)x[sid * 2 + 1];

    double h1[H1D];
    #pragma unroll
    for (int k = 0; k < H1D; ++k)
        h1[k] = tanh(fma(x0, w1d[k], fma(x1, w1d[H1D + k], b1d[k])));

    double h2[H2D];
    #pragma unroll
    for (int m = 0; m < H2D; ++m) {
        double acc = b2d[m];
        #pragma unroll
        for (int k = 0; k < H1D; ++k) acc = fma(h1[k], w2d[k * H2D + m], acc);
        h2[m] = tanh(acc);
    }

    float4 sv;
    float* svp = (float*)&sv;
    #pragma unroll
    for (int q = 0; q < 4; ++q) {
        double acc = cbd[q];
        #pragma unroll
        for (int k = 0; k < H2D; ++k) acc = fma(h2[k], cgd[q][k], acc);
        const double num = (q & 1) ? 3.0 : 1.0;   // 1/g, 3/v, 1/v3, 3/v8
        svp[q] = (float)(num / acc);
    }

    float4* h2o = (float4*)(h2f_out + (size_t)sid * H2D);
    #pragma unroll
    for (int q5 = 0; q5 < 5; ++q5) {
        float4 v;
        v.x = (float)h2[4 * q5 + 0]; v.y = (float)h2[4 * q5 + 1];
        v.z = (float)h2[4 * q5 + 2]; v.w = (float)h2[4 * q5 + 3];
        h2o[q5] = v;
    }
    scl_out[sid] = sv;
}

// ---------------- K2: fp32 back-end GEMM + scale + store ----------------
#define K2_BLK  256
#define K2_SPB  64                     // samples per block
#define K2_NBLK (BATCH / K2_SPB)       // 2048

__global__ __launch_bounds__(K2_BLK) void backend_kernel(
    const float* __restrict__ h2f_in, const float4* __restrict__ scl_in,
    const float* __restrict__ W3, const float* __restrict__ b3,
    float* __restrict__ out)
{
    __shared__ __align__(16) float sh2[K2_SPB * H2D];   // 5 KB
    __shared__ float4 ssc[K2_SPB];                      // 1 KB

    const int t = threadIdx.x;

    // W3 columns into registers: thread t owns columns t, t+256, t+512
    float w3r[3][H2D];
    float b3r[3];
    #pragma unroll
    for (int c = 0; c < 3; ++c) {
        const int j = t + K2_BLK * c;
        if (j < OUTD) {
            b3r[c] = b3[j];
            #pragma unroll
            for (int k = 0; k < H2D; ++k) w3r[c][k] = W3[k * OUTD + j];
        } else {
            b3r[c] = 0.0f;
            #pragma unroll
            for (int k = 0; k < H2D; ++k) w3r[c][k] = 0.0f;
        }
    }

    int bkt[3];
    #pragma unroll
    for (int c = 0; c < 3; ++c) {
        const int j = t + K2_BLK * c;
        int b = 0;
        if      (j >= 50  && j < 150) b = 1;
        else if (j >= 150 && j < 200) b = 2;
        else if (j >= 200 && j < 250) b = 3;
        else if (j >= 250 && j < 300) b = 4;
        bkt[c] = b;
    }

    // stage this block's h2 + scales into LDS (coalesced float4 loads)
    const float4* h2src = (const float4*)(h2f_in + (size_t)blockIdx.x * K2_SPB * H2D);
    #pragma unroll
    for (int i = t; i < (K2_SPB * H2D) / 4; i += K2_BLK)
        ((float4*)sh2)[i] = h2src[i];
    if (t < K2_SPB) ssc[t] = scl_in[blockIdx.x * K2_SPB + t];
    __syncthreads();

    const size_t rowbase = (size_t)blockIdx.x * K2_SPB * OUTD;

    for (int s = 0; s < K2_SPB; ++s) {
        float h[H2D];
        #pragma unroll
        for (int q5 = 0; q5 < 5; ++q5) {
            const float4 hv = *reinterpret_cast<const float4*>(&sh2[s * H2D + 4 * q5]);
            h[4 * q5 + 0] = hv.x; h[4 * q5 + 1] = hv.y;
            h[4 * q5 + 2] = hv.z; h[4 * q5 + 3] = hv.w;
        }
        const float4 sv = ssc[s];
        const size_t row = rowbase + (size_t)s * OUTD;
        #pragma unroll
        for (int c = 0; c < 3; ++c) {
            const int j = t + K2_BLK * c;
            if (j < OUTD) {
                float acc = b3r[c];
                #pragma unroll
                for (int k = 0; k < H2D; ++k) acc = fmaf(h[k], w3r[c][k], acc);
                float sc = 1.0f;
                if      (bkt[c] == 1) sc = sv.x;
                else if (bkt[c] == 2) sc = sv.y;
                else if (bkt[c] == 3) sc = sv.z;
                else if (bkt[c] == 4) sc = sv.w;
                out[row + j] = acc * sc;
            }
        }
    }
}

extern "C" void kernel_launch(void* const* d_in, const int* in_sizes, int n_in,
                              void* d_out, int out_size, void* d_ws, size_t ws_size,
                              hipStream_t stream) {
    const float* x  = (const float*)d_in[0];
    const float* W1 = (const float*)d_in[1];
    const float* b1 = (const float*)d_in[2];
    const float* W2 = (const float*)d_in[3];
    const float* b2 = (const float*)d_in[4];
    const float* W3 = (const float*)d_in[5];
    const float* b3 = (const float*)d_in[6];
    float* out = (float*)d_out;

    float*  h2f = (float*)d_ws;                                   // 131072*20 f32 = 10.5 MB
    float4* scl = (float4*)((char*)d_ws + (size_t)BATCH * H2D * 4); // +2 MB, 16B aligned

    hipLaunchKernelGGL(frontend_kernel, dim3(K1_NBLK), dim3(K1_BLK), 0, stream,
                       x, W1, b1, W2, b2, W3, b3, h2f, scl);
    hipLaunchKernelGGL(backend_kernel, dim3(K2_NBLK), dim3(K2_BLK), 0, stream,
                       h2f, scl, W3, b3, out);
}